// Round 18
// baseline (57.584 us; speedup 1.0000x reference)
//
#include <hip/hip_runtime.h>
#include <math.h>

// NoisyTopKGating via fp16x2-split MFMA — single fused kernel, 16 waves/block.
// BM=64 rows/block, full K=2048, grid 256 (1 block/CU), 1024 threads = 16 waves
// (4 rg x 16 rows, 4 cg x 32 cols; per-wave acc = 16 VGPR). x staged via
// global_load_lds by waves 0-7 only (NBUF=4 x 8KB); W via register pipeline
// (plain float4 loads from packed frags, parity slots, dist-2). Counted vmcnt is
// per-wave-type: stagers vmcnt(6), non-stagers vmcnt(4) — each drains {x(t),W(t)}.
// Fused epilogue (softplus/noise/top-2/softmax); no partials, no reduce kernel.
// out layout (f32 flat): weights [N,2] @0, indices-as-float [N,2] @32768, clean [N,64] @65536.
// d_ws: Bh packed frags (512KB) @0, Bl packed frags (512KB) @+262144 f16.
// Packed W layout (f16 units): [(kc*8 + cg*2 + cf)*512 + lane*8 + j]
//   col = cg*32 + cf*16 + (lane&15),  k = kc*32 + (lane>>4)*8 + j.

constexpr int NROWS = 16384;
constexpr int DDIM  = 2048;
constexpr int EDIM  = 64;
constexpr int BM    = 64;             // rows per block
constexpr int NKS   = 64;             // k-steps of 32
constexpr int LSTR  = 132;            // epilogue LDS stride (floats)
constexpr int IDX_OFF   = NROWS * 2;
constexpr int CLEAN_OFF = NROWS * 4;
constexpr size_t WPACK = 262144;      // f16 elements per packed matrix (128*2048)
constexpr int XS    = 8192;           // x buffer: [64 rows][32 k] f32
constexpr int NBUF  = 4;              // 32KB staging
constexpr int LDSSZ = 33792;          // max(32KB staging, 64*132*4 epilogue)

typedef _Float16 f16x8 __attribute__((ext_vector_type(8)));
typedef float    f32x4 __attribute__((ext_vector_type(4)));

__device__ __forceinline__ float softplus_f(float z) {
    return fmaxf(z, 0.0f) + log1pf(expf(-fabsf(z)));
}

__device__ __forceinline__ void gload16(const void* g, void* l) {
    __builtin_amdgcn_global_load_lds(
        (const __attribute__((address_space(1))) unsigned int*)g,
        (__attribute__((address_space(3))) unsigned int*)l, 16, 0, 0);
}

// ---------- pre-kernel: split + pack weights into frag-ordered hi/lo ----------
__global__ __launch_bounds__(256) void split_w_kernel(
    const float* __restrict__ Wg, const float* __restrict__ Wn,
    _Float16* __restrict__ wh, _Float16* __restrict__ wl)
{
    const int t    = blockIdx.x * 256 + threadIdx.x;   // 0..32767
    const int grp  = t >> 6;                           // kc*8 + cg*2 + cf  (0..511)
    const int lane = t & 63;
    const int kc   = grp >> 3;
    const int cg   = (grp >> 1) & 3;
    const int cf   = grp & 1;
    const int col  = cg * 32 + cf * 16 + (lane & 15);
    const int k0   = kc * 32 + (lane >> 4) * 8;
    const float* src = (col < 64) ? &Wg[(size_t)col * DDIM + k0]
                                  : &Wn[(size_t)(col - 64) * DDIM + k0];
    const float4 v0 = *reinterpret_cast<const float4*>(src);
    const float4 v1 = *reinterpret_cast<const float4*>(src + 4);
    float vv[8] = {v0.x, v0.y, v0.z, v0.w, v1.x, v1.y, v1.z, v1.w};
    union { _Float16 h[8]; uint4 u; } hh, ll;
    #pragma unroll
    for (int j = 0; j < 8; ++j) {
        hh.h[j] = (_Float16)vv[j];
        ll.h[j] = (_Float16)((vv[j] - (float)hh.h[j]) * 2048.0f);
    }
    const size_t off = (size_t)grp * 512 + lane * 8;
    *reinterpret_cast<uint4*>(&wh[off]) = hh.u;
    *reinterpret_cast<uint4*>(&wl[off]) = ll.u;
}

__device__ __forceinline__ void split8(const float4 a, const float4 b, f16x8& h, f16x8& l) {
    const float v[8] = {a.x, a.y, a.z, a.w, b.x, b.y, b.z, b.w};
    #pragma unroll
    for (int j = 0; j < 8; ++j) {
        const _Float16 hh = (_Float16)v[j];
        h[j] = hh;
        l[j] = (_Float16)((v[j] - (float)hh) * 2048.0f);
    }
}

// ---------- main fused kernel: 64 rows x 128 cols x K=2048, 16 waves ----------
__global__ __launch_bounds__(1024, 4) void gating_mfma_kernel(
    const float* __restrict__ x,
    const float* __restrict__ noise,
    const _Float16* __restrict__ whp,
    const _Float16* __restrict__ wlp,
    float* __restrict__ out)
{
    extern __shared__ __align__(16) unsigned char smem[];   // 33792 B

    const int tid  = threadIdx.x;
    const int lane = tid & 63;
    const int wid  = tid >> 6;            // 0..15
    const int rg   = wid >> 2;            // row-group 0..3 (16 rows each)
    const int cg   = wid & 3;             // col-group 0..3 (32 cols each)
    const int g    = (lane >> 4) & 3;
    const int idx  = lane & 15;
    const int row_base = blockIdx.x * BM;

    // ---- x staging (waves 0-7 only): 512 threads x 16B = 8KB chunk ----
    const int sr  = (tid >> 3) & 63;      // row 0..63
    const int sq  = tid & 7;
    const int sq2 = sq ^ (sr & 7);        // pre-swizzled source slot
    const float* xsrc = x + (size_t)(row_base + sr) * DDIM + sq2 * 4;

    // ---- W base pointers (fragment-packed; per-wave 1KB contiguous per load) ----
    const char* bh2 = (const char*)whp + (cg * 2) * 1024 + lane * 16;
    const char* bl2 = (const char*)wlp + (cg * 2) * 1024 + lane * 16;

    // ---- A-frag read offsets (swizzled): row = rg*16 + idx ----
    int aoff[2];
    {
        const int row = rg * 16 + idx;
        #pragma unroll
        for (int j = 0; j < 2; ++j)
            aoff[j] = row * 128 + (((2 * g + j) ^ (row & 7)) << 4);
    }

    f32x4 accm[2], accc[2];
    accm[0] = (f32x4)0.0f; accm[1] = (f32x4)0.0f;
    accc[0] = (f32x4)0.0f; accc[1] = (f32x4)0.0f;

    auto stageX = [&](int u) {
        if (wid < 8)
            gload16(xsrc + u * 32, smem + (u & (NBUF - 1)) * XS + tid * 16);
    };
    auto loadW = [&](int u, float4& h0, float4& h1, float4& l0, float4& l1) {
        const char* ph = bh2 + (size_t)u * 8192;
        const char* pl = bl2 + (size_t)u * 8192;
        h0 = *reinterpret_cast<const float4*>(ph);
        h1 = *reinterpret_cast<const float4*>(ph + 1024);
        l0 = *reinterpret_cast<const float4*>(pl);
        l1 = *reinterpret_cast<const float4*>(pl + 1024);
    };

    auto compute = [&](int t, const float4& h0, const float4& h1,
                       const float4& l0, const float4& l1) {
        const int b = (t & (NBUF - 1)) * XS;
        const float4 a0 = *reinterpret_cast<const float4*>(&smem[b + aoff[0]]);
        const float4 a1 = *reinterpret_cast<const float4*>(&smem[b + aoff[1]]);
        const f16x8 Bh0 = __builtin_bit_cast(f16x8, h0);
        const f16x8 Bh1 = __builtin_bit_cast(f16x8, h1);
        const f16x8 Bl0 = __builtin_bit_cast(f16x8, l0);
        const f16x8 Bl1 = __builtin_bit_cast(f16x8, l1);

        f16x8 Ah, Al;
        split8(a0, a1, Ah, Al);

        accm[0] = __builtin_amdgcn_mfma_f32_16x16x32_f16(Ah, Bh0, accm[0], 0, 0, 0);
        accm[1] = __builtin_amdgcn_mfma_f32_16x16x32_f16(Ah, Bh1, accm[1], 0, 0, 0);
        accc[0] = __builtin_amdgcn_mfma_f32_16x16x32_f16(Al, Bh0, accc[0], 0, 0, 0);
        accc[1] = __builtin_amdgcn_mfma_f32_16x16x32_f16(Al, Bh1, accc[1], 0, 0, 0);
        accc[0] = __builtin_amdgcn_mfma_f32_16x16x32_f16(Ah, Bl0, accc[0], 0, 0, 0);
        accc[1] = __builtin_amdgcn_mfma_f32_16x16x32_f16(Ah, Bl1, accc[1], 0, 0, 0);
    };

    // ---- W register slots (parity) ----
    float4 s0h0, s0h1, s0l0, s0l1, s1h0, s1h1, s1l0, s1l1;

    // ---- prologue: x0,W0,x1,W1 ----
    stageX(0); loadW(0, s0h0, s0h1, s0l0, s0l1);
    stageX(1); loadW(1, s1h0, s1h1, s1l0, s1l1);
    __builtin_amdgcn_sched_barrier(0);

    // ---- main loop: t = 0..61 in parity pairs ----
    // Body: stageX(t+2) | wait (stagers vmcnt(6), others vmcnt(4)) | barrier
    //       | compute(t) | loadW(t+2)
    for (int tt = 0; tt < 31; ++tt) {
        const int t0 = 2 * tt;
        stageX(t0 + 2);
        if (wid < 8) asm volatile("s_waitcnt vmcnt(6)" ::: "memory");
        else         asm volatile("s_waitcnt vmcnt(4)" ::: "memory");
        __builtin_amdgcn_s_barrier();
        __builtin_amdgcn_sched_barrier(0);
        compute(t0, s0h0, s0h1, s0l0, s0l1);
        loadW(t0 + 2, s0h0, s0h1, s0l0, s0l1);
        __builtin_amdgcn_sched_barrier(0);
        stageX(t0 + 3);
        if (wid < 8) asm volatile("s_waitcnt vmcnt(6)" ::: "memory");
        else         asm volatile("s_waitcnt vmcnt(4)" ::: "memory");
        __builtin_amdgcn_s_barrier();
        __builtin_amdgcn_sched_barrier(0);
        compute(t0 + 1, s1h0, s1h1, s1l0, s1l1);
        loadW(t0 + 3, s1h0, s1h1, s1l0, s1l1);
        __builtin_amdgcn_sched_barrier(0);
    }
    // ---- tail t=62: stagers have x(63)+W(63)=5 newer; others W(63)=4 ----
    if (wid < 8) asm volatile("s_waitcnt vmcnt(5)" ::: "memory");
    else         asm volatile("s_waitcnt vmcnt(4)" ::: "memory");
    __builtin_amdgcn_s_barrier();
    __builtin_amdgcn_sched_barrier(0);
    compute(62, s0h0, s0h1, s0l0, s0l1);
    // ---- tail t=63 ----
    asm volatile("s_waitcnt vmcnt(0)" ::: "memory");
    __builtin_amdgcn_s_barrier();
    __builtin_amdgcn_sched_barrier(0);
    compute(63, s1h0, s1h1, s1l0, s1l1);

    __syncthreads();                      // staging done; reuse smem for epilogue

    // ---- epilogue: logits -> LDS [64][132] f32 ----
    float* L = reinterpret_cast<float*>(smem);
    #pragma unroll
    for (int cf = 0; cf < 2; ++cf) {
        const int col = cg * 32 + cf * 16 + idx;
        #pragma unroll
        for (int q = 0; q < 4; ++q) {
            const int lrow = rg * 16 + g * 4 + q;
            L[lrow * LSTR + col] = accm[cf][q] + accc[cf][q] * 4.8828125e-4f;
        }
    }
    __syncthreads();

    // ---- fused softplus/noise/top-2/softmax: 8 threads per row, 64 rows ----
    if (tid < 512) {
        const int row = tid >> 3;
        const int j   = tid & 7;
        const int e0  = j * 8;
        const int grow = row_base + row;

        const float4 c0 = *reinterpret_cast<const float4*>(&L[row * LSTR + e0]);
        const float4 c1 = *reinterpret_cast<const float4*>(&L[row * LSTR + e0 + 4]);
        const float4 s0 = *reinterpret_cast<const float4*>(&L[row * LSTR + 64 + e0]);
        const float4 s1 = *reinterpret_cast<const float4*>(&L[row * LSTR + 64 + e0 + 4]);
        *reinterpret_cast<float4*>(&out[CLEAN_OFF + (size_t)grow * EDIM + e0])     = c0;
        *reinterpret_cast<float4*>(&out[CLEAN_OFF + (size_t)grow * EDIM + e0 + 4]) = c1;

        const float4 z0 = *reinterpret_cast<const float4*>(&noise[(size_t)grow * EDIM + e0]);
        const float4 z1 = *reinterpret_cast<const float4*>(&noise[(size_t)grow * EDIM + e0 + 4]);

        float nv[8];
        nv[0] = fmaf(softplus_f(s0.x), z0.x, c0.x);
        nv[1] = fmaf(softplus_f(s0.y), z0.y, c0.y);
        nv[2] = fmaf(softplus_f(s0.z), z0.z, c0.z);
        nv[3] = fmaf(softplus_f(s0.w), z0.w, c0.w);
        nv[4] = fmaf(softplus_f(s1.x), z1.x, c1.x);
        nv[5] = fmaf(softplus_f(s1.y), z1.y, c1.y);
        nv[6] = fmaf(softplus_f(s1.z), z1.z, c1.z);
        nv[7] = fmaf(softplus_f(s1.w), z1.w, c1.w);

        float v0 = nv[0], v1 = -INFINITY;
        int   i0 = e0,    i1 = -1;
        #pragma unroll
        for (int m = 1; m < 8; ++m) {
            const float v = nv[m]; const int e = e0 + m;
            if (v > v0)      { v1 = v0; i1 = i0; v0 = v; i0 = e; }
            else if (v > v1) { v1 = v;  i1 = e; }
        }
        #pragma unroll
        for (int d = 1; d < 8; d <<= 1) {
            const float ov0 = __shfl_xor(v0, d); const int oi0 = __shfl_xor(i0, d);
            const float ov1 = __shfl_xor(v1, d); const int oi1 = __shfl_xor(i1, d);
            const bool aFirst = (v0 > ov0) || (v0 == ov0 && i0 < oi0);
            float n0, n1; int ni0, ni1;
            if (aFirst) {
                n0 = v0; ni0 = i0;
                const bool s = (v1 > ov0) || (v1 == ov0 && i1 < oi0);
                n1 = s ? v1 : ov0; ni1 = s ? i1 : oi0;
            } else {
                n0 = ov0; ni0 = oi0;
                const bool s = (ov1 > v0) || (ov1 == v0 && oi1 < i0);
                n1 = s ? ov1 : v0; ni1 = s ? oi1 : i0;
            }
            v0 = n0; i0 = ni0; v1 = n1; i1 = ni1;
        }
        if (j == 0) {
            const float ex = expf(v1 - v0);
            const float w0 = 1.0f / (1.0f + ex);
            const float w1 = 1.0f - w0;
            out[(size_t)grow * 2 + 0] = w0;
            out[(size_t)grow * 2 + 1] = w1;
            out[IDX_OFF + (size_t)grow * 2 + 0] = (float)i0;
            out[IDX_OFF + (size_t)grow * 2 + 1] = (float)i1;
        }
    }
}

extern "C" void kernel_launch(void* const* d_in, const int* in_sizes, int n_in,
                              void* d_out, int out_size, void* d_ws, size_t ws_size,
                              hipStream_t stream) {
    const float* x     = (const float*)d_in[0];
    const float* Wg    = (const float*)d_in[1];
    const float* Wn    = (const float*)d_in[2];
    const float* noise = (const float*)d_in[3];
    float* out = (float*)d_out;

    _Float16* wh = (_Float16*)d_ws;
    _Float16* wl = wh + WPACK;               // packed matrix is 262144 f16 (512KB)

    split_w_kernel<<<dim3(128), dim3(256), 0, stream>>>(Wg, Wn, wh, wl);
    gating_mfma_kernel<<<dim3(NROWS / BM), dim3(1024), LDSSZ, stream>>>(x, noise, wh, wl, out);
}